// Round 3
// baseline (51.720 us; speedup 1.0000x reference)
//
#include <hip/hip_runtime.h>

#define GXD 96
#define GYD 96
#define GZD 96
#define PTS_PER_B (GXD * GYD * GZD)
#define ZPT 4
#define SLOTS (GZD / ZPT)                 // 24 threads per z-column
#define THREADS_PER_B (GXD * GYD * SLOTS) // 221184, divisible by 256
#define RECSZ 32                          // floats per (b,n) record
#define BIGF 1e10f
#define GLOWER -1.2f
#define GSTEP 0.025f

// ---------- shared exact math helpers (identical op order to validated round-0/1) ----------
__device__ __forceinline__ void rot_inv(float qx, float qy, float qz, float qw,
                                        float dx, float dy, float dz,
                                        float& rx, float& ry, float& rz)
{
    float ux = -qx, uy = -qy, uz = -qz;
    float uvx = uy * dz - uz * dy;
    float uvy = uz * dx - ux * dz;
    float uvz = ux * dy - uy * dx;
    float t2x = uvx + qw * dx;
    float t2y = uvy + qw * dy;
    float t2z = uvz + qw * dz;
    rx = dx + 2.0f * (uy * t2z - uz * t2y);
    ry = dy + 2.0f * (uz * t2x - ux * t2z);
    rz = dz + 2.0f * (ux * t2y - uy * t2x);
}

// smallest positive float a with fl(a/w) >= target   (w>0, target>0)
__device__ float bisect_lo(float w, float target)
{
    unsigned lo = 0u, hi = 0x7f000000u;   // f(lo)=false (0/w=0<target), f(hi)=true
    while (hi - lo > 1u) {
        unsigned mid = (lo + hi) >> 1;
        float a = __uint_as_float(mid);
        if (a / w >= target) hi = mid; else lo = mid;
    }
    return __uint_as_float(hi);
}

// largest positive float a with fl(a/w) <= limit
__device__ float bisect_hi(float w, float limit)
{
    unsigned lo = 0u, hi = 0x7f000000u;   // g(lo)=true, g(hi)=false (huge/w > limit)
    while (hi - lo > 1u) {
        unsigned mid = (lo + hi) >> 1;
        float a = __uint_as_float(mid);
        if (a / w <= limit) lo = mid; else hi = mid;
    }
    return __uint_as_float(lo);
}

// record layout (floats unless noted):
//  0-2  t        3-6  q(normalized)   7-9  invw (fl(1/w))
// 10-12 m=(S-1)f 13-15 A (exact lo)  16-18 B (exact hi)
// 19-21 Aw=A-1e-4 (margined)         22-24 Bw=B+1e-4
// 25-27 dr = R^-1*(0,0,STEP)
// 28 (int) m*sdf_stride   29-31 (int) SX,SY,SZ
__global__ void prep_v2(const int* __restrict__ shapes,
                        const int* __restrict__ indices,
                        const float* __restrict__ poses,
                        const float* __restrict__ widths,
                        float* __restrict__ rec,
                        int BN, int sdf_stride)
{
    int bn = blockIdx.x * blockDim.x + threadIdx.x;
    if (bn >= BN) return;
    int m = indices[bn];
    const float* pp = poses + (size_t)bn * 7;
    float tx = pp[0], ty = pp[1], tz = pp[2];
    float qx = pp[3], qy = pp[4], qz = pp[5], qw = pp[6];
    // identical op order to validated rounds -> bit-identical q
    float nrm = sqrtf(qx * qx + qy * qy + qz * qz + qw * qw);
    qx = qx / nrm; qy = qy / nrm; qz = qz / nrm; qw = qw / nrm;

    float wx = widths[bn * 3 + 0], wy = widths[bn * 3 + 1], wz = widths[bn * 3 + 2];
    int SX = shapes[m * 3 + 0], SY = shapes[m * 3 + 1], SZ = shapes[m * 3 + 2];
    float mx = (float)(SX - 1), my = (float)(SY - 1), mz = (float)(SZ - 1);

    // exact [A,B] per axis: inside_x <=> fl(rx/w) in [0.5, mx+0.5] <=> rx in [A,B]
    float Ax = bisect_lo(wx, 0.5f), Ay = bisect_lo(wy, 0.5f), Az = bisect_lo(wz, 0.5f);
    float Bx = bisect_hi(wx, mx + 0.5f), By = bisect_hi(wy, my + 0.5f), Bz = bisect_hi(wz, mz + 0.5f);

    // rotated z-step (linear part only; used for margined pre-test, precision uncritical)
    float drx, dry, drz;
    rot_inv(qx, qy, qz, qw, 0.0f, 0.0f, GSTEP, drx, dry, drz);

    const float MRG = 1e-4f;  // >> incremental drift (~2e-6), << box scale

    float* r = rec + (size_t)bn * RECSZ;
    r[0] = tx;  r[1] = ty;  r[2] = tz;
    r[3] = qx;  r[4] = qy;  r[5] = qz;  r[6] = qw;
    r[7] = 1.0f / wx; r[8] = 1.0f / wy; r[9] = 1.0f / wz;
    r[10] = mx; r[11] = my; r[12] = mz;
    r[13] = Ax; r[14] = Ay; r[15] = Az;
    r[16] = Bx; r[17] = By; r[18] = Bz;
    r[19] = Ax - MRG; r[20] = Ay - MRG; r[21] = Az - MRG;
    r[22] = Bx + MRG; r[23] = By + MRG; r[24] = Bz + MRG;
    r[25] = drx; r[26] = dry; r[27] = drz;
    int* ri = (int*)r;
    ri[28] = m * sdf_stride;
    ri[29] = SX; ri[30] = SY; ri[31] = SZ;
}

__device__ __forceinline__ float trilerp(const float* __restrict__ sd,
                                         float rx, float ry, float rz,
                                         float invwx, float invwy, float invwz,
                                         float mx, float my, float mz,
                                         int SX, int SY, int SZ)
{
    // approximate g (reciprocal mul): only affects interpolated VALUE at ~ulp level,
    // inside/outside decision already made exactly via [A,B].
    float gx = rx * invwx - 0.5f;
    float gy = ry * invwy - 0.5f;
    float gz = rz * invwz - 0.5f;
    float fx = fminf(fmaxf(gx, 0.0f), mx);
    float fy = fminf(fmaxf(gy, 0.0f), my);
    float fz = fminf(fmaxf(gz, 0.0f), mz);
    int i0x = (int)fx, i0y = (int)fy, i0z = (int)fz;  // fx>=0 -> trunc==floor
    float frx = fx - (float)i0x;
    float fry = fy - (float)i0y;
    float frz = fz - (float)i0z;
    int i1x = min(i0x + 1, SX - 1);
    int i1y = min(i0y + 1, SY - 1);
    int i1z = min(i0z + 1, SZ - 1);
    int b00 = (i0x * SY + i0y) * SZ;
    int b01 = (i0x * SY + i1y) * SZ;
    int b10 = (i1x * SY + i0y) * SZ;
    int b11 = (i1x * SY + i1y) * SZ;
    float v000 = sd[b00 + i0z], v001 = sd[b00 + i1z];
    float v010 = sd[b01 + i0z], v011 = sd[b01 + i1z];
    float v100 = sd[b10 + i0z], v101 = sd[b10 + i1z];
    float v110 = sd[b11 + i0z], v111 = sd[b11 + i1z];
    float c00 = v000 + frz * (v001 - v000);
    float c01 = v010 + frz * (v011 - v010);
    float c10 = v100 + frz * (v101 - v100);
    float c11 = v110 + frz * (v111 - v110);
    float c0 = c00 + fry * (c01 - c00);
    float c1 = c10 + fry * (c11 - c10);
    return c0 + frx * (c1 - c0);
}

__global__ __launch_bounds__(256) void sdf_grid_v2(
    const float* __restrict__ sdfs,
    const float* __restrict__ rec,
    float* __restrict__ out,
    int N)
{
    int pid = blockIdx.x * blockDim.x + threadIdx.x;  // 0 .. THREADS_PER_B-1
    int b = blockIdx.y;
    int slot = pid % SLOTS;
    int col  = pid / SLOTS;       // x*96 + y
    int y = col % GYD;
    int x = col / GYD;
    int z0 = slot * ZPT;

    float px = GLOWER + ((float)x + 0.5f) * GSTEP;
    float py = GLOWER + ((float)y + 0.5f) * GSTEP;
    float pz0 = GLOWER + ((float)z0 + 0.5f) * GSTEP;

    float best[ZPT];
#pragma unroll
    for (int k = 0; k < ZPT; ++k) best[k] = BIGF;

    for (int n = 0; n < N; ++n) {
        const float* r = rec + (size_t)(b * N + n) * RECSZ;  // uniform address -> s_load
        float tx = r[0], ty = r[1], tz = r[2];
        float qx = r[3], qy = r[4], qz = r[5], qw = r[6];
        float Ax = r[13], Ay = r[14], Az = r[15];
        float Bx = r[16], By = r[17], Bz = r[18];

        float dx = px - tx, dy = py - ty, dz0 = pz0 - tz;
        float rx0, ry0, rz0;
        rot_inv(qx, qy, qz, qw, dx, dy, dz0, rx0, ry0, rz0);

        // ---- point 0: exact test directly ----
        bool in0 = (rx0 >= Ax) & (rx0 <= Bx) &
                   (ry0 >= Ay) & (ry0 <= By) &
                   (rz0 >= Az) & (rz0 <= Bz);
        if (in0) {
            const int* ri = (const int*)r;
            float v = trilerp(sdfs + ri[28], rx0, ry0, rz0,
                              r[7], r[8], r[9], r[10], r[11], r[12],
                              ri[29], ri[30], ri[31]);
            best[0] = fminf(best[0], v);
        }

        // ---- points 1..3: incremental coords, margined pre-test, exact recompute ----
        float Awx = r[19], Awy = r[20], Awz = r[21];
        float Bwx = r[22], Bwy = r[23], Bwz = r[24];
        float drx = r[25], dry = r[26], drz = r[27];
        float rxk = rx0, ryk = ry0, rzk = rz0;
#pragma unroll
        for (int k = 1; k < ZPT; ++k) {
            rxk += drx; ryk += dry; rzk += drz;
            bool maybe = (rxk >= Awx) & (rxk <= Bwx) &
                         (ryk >= Awy) & (ryk <= Bwy) &
                         (rzk >= Awz) & (rzk <= Bwz);
            if (maybe) {
                // exact recompute: identical op chain to validated rounds
                float pzk = GLOWER + ((float)(z0 + k) + 0.5f) * GSTEP;
                float dzk = pzk - tz;
                float rxe, rye, rze;
                rot_inv(qx, qy, qz, qw, dx, dy, dzk, rxe, rye, rze);
                bool ine = (rxe >= Ax) & (rxe <= Bx) &
                           (rye >= Ay) & (rye <= By) &
                           (rze >= Az) & (rze <= Bz);
                if (ine) {
                    const int* ri = (const int*)r;
                    float v = trilerp(sdfs + ri[28], rxe, rye, rze,
                                      r[7], r[8], r[9], r[10], r[11], r[12],
                                      ri[29], ri[30], ri[31]);
                    best[k] = fminf(best[k], v);
                }
            }
        }
    }

    float4 o = make_float4(best[0], best[1], best[2], best[3]);
    *(float4*)(out + (size_t)b * PTS_PER_B + (size_t)col * GZD + z0) = o;
}

// ---------------- fallback: round-0 validated monolithic kernel ----------------
__global__ __launch_bounds__(256) void sdf_grid_kernel(
    const float* __restrict__ sdfs,
    const int*   __restrict__ sdf_shapes,
    const int*   __restrict__ indices,
    const float* __restrict__ poses,
    const float* __restrict__ widths,
    float*       __restrict__ out,
    int total, int N, int sdf_stride)
{
    int idx = blockIdx.x * blockDim.x + threadIdx.x;
    if (idx >= total) return;
    int z = idx % GZD;
    int y = (idx / GZD) % GYD;
    int x = (idx / (GZD * GYD)) % GXD;
    int b = idx / (GZD * GYD * GXD);
    float px = GLOWER + ((float)x + 0.5f) * GSTEP;
    float py = GLOWER + ((float)y + 0.5f) * GSTEP;
    float pz = GLOWER + ((float)z + 0.5f) * GSTEP;
    float best = BIGF;
    for (int n = 0; n < N; ++n) {
        int bn = b * N + n;
        int m  = indices[bn];
        const float* pp = poses + (size_t)bn * 7;
        float tx = pp[0], ty = pp[1], tz = pp[2];
        float qx = pp[3], qy = pp[4], qz = pp[5], qw = pp[6];
        float nrm = sqrtf(qx * qx + qy * qy + qz * qz + qw * qw);
        qx = qx / nrm; qy = qy / nrm; qz = qz / nrm; qw = qw / nrm;
        float dx = px - tx, dy = py - ty, dz = pz - tz;
        float rx, ry, rz;
        rot_inv(qx, qy, qz, qw, dx, dy, dz, rx, ry, rz);
        const float* ww = widths + (size_t)bn * 3;
        float gx = rx / ww[0] - 0.5f;
        float gy = ry / ww[1] - 0.5f;
        float gz = rz / ww[2] - 0.5f;
        int SX = sdf_shapes[m * 3 + 0];
        int SY = sdf_shapes[m * 3 + 1];
        int SZ = sdf_shapes[m * 3 + 2];
        float mx = (float)(SX - 1), my = (float)(SY - 1), mz = (float)(SZ - 1);
        bool inside = (gx >= 0.0f) && (gx <= mx) &&
                      (gy >= 0.0f) && (gy <= my) &&
                      (gz >= 0.0f) && (gz <= mz);
        float fx = fminf(fmaxf(gx, 0.0f), mx);
        float fy = fminf(fmaxf(gy, 0.0f), my);
        float fz = fminf(fmaxf(gz, 0.0f), mz);
        int i0x = (int)floorf(fx), i0y = (int)floorf(fy), i0z = (int)floorf(fz);
        float frx = fx - (float)i0x, fry = fy - (float)i0y, frz = fz - (float)i0z;
        int i1x = min(i0x + 1, SX - 1);
        int i1y = min(i0y + 1, SY - 1);
        int i1z = min(i0z + 1, SZ - 1);
        const float* sd = sdfs + (size_t)m * sdf_stride;
        int b00 = (i0x * SY + i0y) * SZ;
        int b01 = (i0x * SY + i1y) * SZ;
        int b10 = (i1x * SY + i0y) * SZ;
        int b11 = (i1x * SY + i1y) * SZ;
        float v000 = sd[b00 + i0z], v001 = sd[b00 + i1z];
        float v010 = sd[b01 + i0z], v011 = sd[b01 + i1z];
        float v100 = sd[b10 + i0z], v101 = sd[b10 + i1z];
        float v110 = sd[b11 + i0z], v111 = sd[b11 + i1z];
        float wx0 = 1.0f - frx, wx1 = frx;
        float wy0 = 1.0f - fry, wy1 = fry;
        float wz0 = 1.0f - frz, wz1 = frz;
        float acc = wx0 * wy0 * wz0 * v000 + wx0 * wy0 * wz1 * v001
                  + wx0 * wy1 * wz0 * v010 + wx0 * wy1 * wz1 * v011
                  + wx1 * wy0 * wz0 * v100 + wx1 * wy0 * wz1 * v101
                  + wx1 * wy1 * wz0 * v110 + wx1 * wy1 * wz1 * v111;
        float val = inside ? acc : BIGF;
        best = fminf(best, val);
    }
    out[idx] = best;
}

extern "C" void kernel_launch(void* const* d_in, const int* in_sizes, int n_in,
                              void* d_out, int out_size, void* d_ws, size_t ws_size,
                              hipStream_t stream) {
    const float* sdfs    = (const float*)d_in[0];
    const int*   shapes  = (const int*)d_in[1];
    const int*   indices = (const int*)d_in[2];
    const float* poses   = (const float*)d_in[3];
    const float* widths  = (const float*)d_in[4];
    float*       out     = (float*)d_out;

    int M = in_sizes[1] / 3;           // sdf_shapes is (M,3)
    int sdf_stride = in_sizes[0] / M;  // elements per SDF volume
    int B = out_size / PTS_PER_B;
    int N = in_sizes[2] / B;           // indices is (B,N)
    int BN = B * N;

    size_t ws_needed = (size_t)BN * RECSZ * sizeof(float);
    if (ws_size >= ws_needed && (THREADS_PER_B % 256) == 0) {
        float* rec = (float*)d_ws;
        int pthreads = 64;
        int pblocks = (BN + pthreads - 1) / pthreads;
        prep_v2<<<pblocks, pthreads, 0, stream>>>(
            shapes, indices, poses, widths, rec, BN, sdf_stride);
        dim3 grid(THREADS_PER_B / 256, B);
        sdf_grid_v2<<<grid, 256, 0, stream>>>(sdfs, rec, out, N);
    } else {
        int total = out_size;
        int blocks = (total + 255) / 256;
        sdf_grid_kernel<<<blocks, 256, 0, stream>>>(
            sdfs, shapes, indices, poses, widths, out, total, N, sdf_stride);
    }
}

// Round 4
// 43.060 us; speedup vs baseline: 1.2011x; 1.2011x over previous
//
#include <hip/hip_runtime.h>

#define GXD 96
#define GYD 96
#define GZD 96
#define PTS_PER_B (GXD * GYD * GZD)
#define RECSZ 24
#define BIGF 1e10f
#define GLOWER -1.2f
#define GSTEP 0.025f

// ---------- exact rotate: identical op order to validated round-0/1 ----------
__device__ __forceinline__ void rot_inv(float qx, float qy, float qz, float qw,
                                        float dx, float dy, float dz,
                                        float& rx, float& ry, float& rz)
{
    float ux = -qx, uy = -qy, uz = -qz;
    float uvx = uy * dz - uz * dy;
    float uvy = uz * dx - ux * dz;
    float uvz = ux * dy - uy * dx;
    float t2x = uvx + qw * dx;
    float t2y = uvy + qw * dy;
    float t2z = uvz + qw * dz;
    rx = dx + 2.0f * (uy * t2z - uz * t2y);
    ry = dy + 2.0f * (uz * t2x - ux * t2z);
    rz = dz + 2.0f * (ux * t2y - uy * t2x);
}

// smallest positive float a with fl(a/w) >= target   (w>0, target>0)
__device__ float bisect_lo(float w, float target)
{
    unsigned lo = 0u, hi = 0x7f000000u;
    while (hi - lo > 1u) {
        unsigned mid = (lo + hi) >> 1;
        float a = __uint_as_float(mid);
        if (a / w >= target) hi = mid; else lo = mid;
    }
    return __uint_as_float(hi);
}

// largest positive float a with fl(a/w) <= limit
__device__ float bisect_hi(float w, float limit)
{
    unsigned lo = 0u, hi = 0x7f000000u;
    while (hi - lo > 1u) {
        unsigned mid = (lo + hi) >> 1;
        float a = __uint_as_float(mid);
        if (a / w <= limit) lo = mid; else hi = mid;
    }
    return __uint_as_float(lo);
}

// record layout (floats unless noted):
//  0-2  t      3-6  q(normalized)    7-9  invw=fl(1/w)
// 10-12 (S-1)f 13-15 A (exact lo)   16-18 B (exact hi)
// 19 (int) m*sdf_stride  20-22 (int) SX,SY,SZ  23 pad
// inside_x <=> fl(rx/w) in [0.5, mx+0.5] <=> rx in [A,B]  (exact: division is
// monotone; u-0.5 is Sterbenz-exact on the decision range; |u|<2^23 here)
__global__ void prep_v3(const int* __restrict__ shapes,
                        const int* __restrict__ indices,
                        const float* __restrict__ poses,
                        const float* __restrict__ widths,
                        float* __restrict__ rec,
                        int BN, int sdf_stride)
{
    int bn = blockIdx.x * blockDim.x + threadIdx.x;
    if (bn >= BN) return;
    int m = indices[bn];
    const float* pp = poses + (size_t)bn * 7;
    float tx = pp[0], ty = pp[1], tz = pp[2];
    float qx = pp[3], qy = pp[4], qz = pp[5], qw = pp[6];
    // identical op order to validated rounds -> bit-identical q
    float nrm = sqrtf(qx * qx + qy * qy + qz * qz + qw * qw);
    qx = qx / nrm; qy = qy / nrm; qz = qz / nrm; qw = qw / nrm;

    float wx = widths[bn * 3 + 0], wy = widths[bn * 3 + 1], wz = widths[bn * 3 + 2];
    int SX = shapes[m * 3 + 0], SY = shapes[m * 3 + 1], SZ = shapes[m * 3 + 2];
    float mx = (float)(SX - 1), my = (float)(SY - 1), mz = (float)(SZ - 1);

    float Ax = bisect_lo(wx, 0.5f), Ay = bisect_lo(wy, 0.5f), Az = bisect_lo(wz, 0.5f);
    float Bx = bisect_hi(wx, mx + 0.5f), By = bisect_hi(wy, my + 0.5f), Bz = bisect_hi(wz, mz + 0.5f);

    float* r = rec + (size_t)bn * RECSZ;
    r[0] = tx;  r[1] = ty;  r[2] = tz;
    r[3] = qx;  r[4] = qy;  r[5] = qz;  r[6] = qw;
    r[7] = 1.0f / wx; r[8] = 1.0f / wy; r[9] = 1.0f / wz;
    r[10] = mx; r[11] = my; r[12] = mz;
    r[13] = Ax; r[14] = Ay; r[15] = Az;
    r[16] = Bx; r[17] = By; r[18] = Bz;
    int* ri = (int*)r;
    ri[19] = m * sdf_stride;
    ri[20] = SX; ri[21] = SY; ri[22] = SZ;
    r[23] = 0.0f;
}

__device__ __forceinline__ float trilerp(const float* __restrict__ sd,
                                         float rx, float ry, float rz,
                                         float invwx, float invwy, float invwz,
                                         float mx, float my, float mz,
                                         int SX, int SY, int SZ)
{
    // reciprocal-mul g: affects interpolated VALUE only at ~ulp level;
    // the inside/outside decision was already made exactly via [A,B].
    float gx = rx * invwx - 0.5f;
    float gy = ry * invwy - 0.5f;
    float gz = rz * invwz - 0.5f;
    float fx = fminf(fmaxf(gx, 0.0f), mx);
    float fy = fminf(fmaxf(gy, 0.0f), my);
    float fz = fminf(fmaxf(gz, 0.0f), mz);
    int i0x = (int)fx, i0y = (int)fy, i0z = (int)fz;  // f>=0 -> trunc==floor
    float frx = fx - (float)i0x;
    float fry = fy - (float)i0y;
    float frz = fz - (float)i0z;
    int i1x = min(i0x + 1, SX - 1);
    int i1y = min(i0y + 1, SY - 1);
    int i1z = min(i0z + 1, SZ - 1);
    int b00 = (i0x * SY + i0y) * SZ;
    int b01 = (i0x * SY + i1y) * SZ;
    int b10 = (i1x * SY + i0y) * SZ;
    int b11 = (i1x * SY + i1y) * SZ;
    float v000 = sd[b00 + i0z], v001 = sd[b00 + i1z];
    float v010 = sd[b01 + i0z], v011 = sd[b01 + i1z];
    float v100 = sd[b10 + i0z], v101 = sd[b10 + i1z];
    float v110 = sd[b11 + i0z], v111 = sd[b11 + i1z];
    float c00 = v000 + frz * (v001 - v000);
    float c01 = v010 + frz * (v011 - v010);
    float c10 = v100 + frz * (v101 - v100);
    float c11 = v110 + frz * (v111 - v110);
    float c0 = c00 + fry * (c01 - c00);
    float c1 = c10 + fry * (c11 - c10);
    return c0 + frx * (c1 - c0);
}

__global__ __launch_bounds__(256) void sdf_grid_v3(
    const float* __restrict__ sdfs,
    const float* __restrict__ rec,
    float* __restrict__ out,
    int N)
{
    int pid = blockIdx.x * blockDim.x + threadIdx.x;  // flat within batch, z innermost
    int b = blockIdx.y;

    int z = pid % GZD;
    int y = (pid / GZD) % GYD;
    int x = pid / (GZD * GYD);

    float px = GLOWER + ((float)x + 0.5f) * GSTEP;
    float py = GLOWER + ((float)y + 0.5f) * GSTEP;
    float pz = GLOWER + ((float)z + 0.5f) * GSTEP;

    float best = BIGF;

    for (int n = 0; n < N; ++n) {
        const float* r = rec + (size_t)(b * N + n) * RECSZ;  // wave-uniform -> s_load
        float dx = px - r[0], dy = py - r[1], dz = pz - r[2];
        float rx, ry, rz;
        rot_inv(r[3], r[4], r[5], r[6], dx, dy, dz, rx, ry, rz);

        // single exact inside test, no divisions
        bool inside = (rx >= r[13]) & (rx <= r[16]) &
                      (ry >= r[14]) & (ry <= r[17]) &
                      (rz >= r[15]) & (rz <= r[18]);
        if (inside) {
            const int* ri = (const int*)r;
            float v = trilerp(sdfs + ri[19], rx, ry, rz,
                              r[7], r[8], r[9], r[10], r[11], r[12],
                              ri[20], ri[21], ri[22]);
            best = fminf(best, v);
        }
    }

    out[(size_t)b * PTS_PER_B + pid] = best;
}

// ---------------- fallback: round-0 validated monolithic kernel ----------------
__global__ __launch_bounds__(256) void sdf_grid_kernel(
    const float* __restrict__ sdfs,
    const int*   __restrict__ sdf_shapes,
    const int*   __restrict__ indices,
    const float* __restrict__ poses,
    const float* __restrict__ widths,
    float*       __restrict__ out,
    int total, int N, int sdf_stride)
{
    int idx = blockIdx.x * blockDim.x + threadIdx.x;
    if (idx >= total) return;
    int z = idx % GZD;
    int y = (idx / GZD) % GYD;
    int x = (idx / (GZD * GYD)) % GXD;
    int b = idx / (GZD * GYD * GXD);
    float px = GLOWER + ((float)x + 0.5f) * GSTEP;
    float py = GLOWER + ((float)y + 0.5f) * GSTEP;
    float pz = GLOWER + ((float)z + 0.5f) * GSTEP;
    float best = BIGF;
    for (int n = 0; n < N; ++n) {
        int bn = b * N + n;
        int m  = indices[bn];
        const float* pp = poses + (size_t)bn * 7;
        float tx = pp[0], ty = pp[1], tz = pp[2];
        float qx = pp[3], qy = pp[4], qz = pp[5], qw = pp[6];
        float nrm = sqrtf(qx * qx + qy * qy + qz * qz + qw * qw);
        qx = qx / nrm; qy = qy / nrm; qz = qz / nrm; qw = qw / nrm;
        float dx = px - tx, dy = py - ty, dz = pz - tz;
        float rx, ry, rz;
        rot_inv(qx, qy, qz, qw, dx, dy, dz, rx, ry, rz);
        const float* ww = widths + (size_t)bn * 3;
        float gx = rx / ww[0] - 0.5f;
        float gy = ry / ww[1] - 0.5f;
        float gz = rz / ww[2] - 0.5f;
        int SX = sdf_shapes[m * 3 + 0];
        int SY = sdf_shapes[m * 3 + 1];
        int SZ = sdf_shapes[m * 3 + 2];
        float mx = (float)(SX - 1), my = (float)(SY - 1), mz = (float)(SZ - 1);
        bool inside = (gx >= 0.0f) && (gx <= mx) &&
                      (gy >= 0.0f) && (gy <= my) &&
                      (gz >= 0.0f) && (gz <= mz);
        float fx = fminf(fmaxf(gx, 0.0f), mx);
        float fy = fminf(fmaxf(gy, 0.0f), my);
        float fz = fminf(fmaxf(gz, 0.0f), mz);
        int i0x = (int)floorf(fx), i0y = (int)floorf(fy), i0z = (int)floorf(fz);
        float frx = fx - (float)i0x, fry = fy - (float)i0y, frz = fz - (float)i0z;
        int i1x = min(i0x + 1, SX - 1);
        int i1y = min(i0y + 1, SY - 1);
        int i1z = min(i0z + 1, SZ - 1);
        const float* sd = sdfs + (size_t)m * sdf_stride;
        int b00 = (i0x * SY + i0y) * SZ;
        int b01 = (i0x * SY + i1y) * SZ;
        int b10 = (i1x * SY + i0y) * SZ;
        int b11 = (i1x * SY + i1y) * SZ;
        float v000 = sd[b00 + i0z], v001 = sd[b00 + i1z];
        float v010 = sd[b01 + i0z], v011 = sd[b01 + i1z];
        float v100 = sd[b10 + i0z], v101 = sd[b10 + i1z];
        float v110 = sd[b11 + i0z], v111 = sd[b11 + i1z];
        float wx0 = 1.0f - frx, wx1 = frx;
        float wy0 = 1.0f - fry, wy1 = fry;
        float wz0 = 1.0f - frz, wz1 = frz;
        float acc = wx0 * wy0 * wz0 * v000 + wx0 * wy0 * wz1 * v001
                  + wx0 * wy1 * wz0 * v010 + wx0 * wy1 * wz1 * v011
                  + wx1 * wy0 * wz0 * v100 + wx1 * wy0 * wz1 * v101
                  + wx1 * wy1 * wz0 * v110 + wx1 * wy1 * wz1 * v111;
        float val = inside ? acc : BIGF;
        best = fminf(best, val);
    }
    out[idx] = best;
}

extern "C" void kernel_launch(void* const* d_in, const int* in_sizes, int n_in,
                              void* d_out, int out_size, void* d_ws, size_t ws_size,
                              hipStream_t stream) {
    const float* sdfs    = (const float*)d_in[0];
    const int*   shapes  = (const int*)d_in[1];
    const int*   indices = (const int*)d_in[2];
    const float* poses   = (const float*)d_in[3];
    const float* widths  = (const float*)d_in[4];
    float*       out     = (float*)d_out;

    int M = in_sizes[1] / 3;           // sdf_shapes is (M,3)
    int sdf_stride = in_sizes[0] / M;  // elements per SDF volume
    int B = out_size / PTS_PER_B;
    int N = in_sizes[2] / B;           // indices is (B,N)
    int BN = B * N;

    size_t ws_needed = (size_t)BN * RECSZ * sizeof(float);
    if (ws_size >= ws_needed && (PTS_PER_B % 256) == 0) {
        float* rec = (float*)d_ws;
        int pthreads = 64;
        int pblocks = (BN + pthreads - 1) / pthreads;
        prep_v3<<<pblocks, pthreads, 0, stream>>>(
            shapes, indices, poses, widths, rec, BN, sdf_stride);
        dim3 grid(PTS_PER_B / 256, B);
        sdf_grid_v3<<<grid, 256, 0, stream>>>(sdfs, rec, out, N);
    } else {
        int total = out_size;
        int blocks = (total + 255) / 256;
        sdf_grid_kernel<<<blocks, 256, 0, stream>>>(
            sdfs, shapes, indices, poses, widths, out, total, N, sdf_stride);
    }
}

// Round 5
// 31.063 us; speedup vs baseline: 1.6650x; 1.3862x over previous
//
#include <hip/hip_runtime.h>

#define GXD 96
#define GYD 96
#define GZD 96
#define PTS_PER_B (GXD * GYD * GZD)
#define BLOCKS_PER_B (PTS_PER_B / 256)   // 3456
#define RECSZ 32
#define BIGF 1e10f
#define GLOWER -1.2f
#define GSTEP 0.025f

// ---------- exact rotate: identical op order to validated rounds ----------
__device__ __forceinline__ void rot_inv(float qx, float qy, float qz, float qw,
                                        float dx, float dy, float dz,
                                        float& rx, float& ry, float& rz)
{
    float ux = -qx, uy = -qy, uz = -qz;
    float uvx = uy * dz - uz * dy;
    float uvy = uz * dx - ux * dz;
    float uvz = ux * dy - uy * dx;
    float t2x = uvx + qw * dx;
    float t2y = uvy + qw * dy;
    float t2z = uvz + qw * dz;
    rx = dx + 2.0f * (uy * t2z - uz * t2y);
    ry = dy + 2.0f * (uz * t2x - ux * t2z);
    rz = dz + 2.0f * (ux * t2y - uy * t2x);
}

__device__ __forceinline__ float next_up(float a) { return __uint_as_float(__float_as_uint(a) + 1u); }
__device__ __forceinline__ float next_dn(float a) { return __uint_as_float(__float_as_uint(a) - 1u); }

// smallest positive float a with fl(a/w) >= t   (w>0, t>0; a* within ~3 ulp of t*w)
__device__ float exact_lo(float w, float t)
{
    float a = t * w;
    while (a / w < t)            a = next_up(a);
    while (next_dn(a) / w >= t)  a = next_dn(a);
    return a;
}

// largest positive float a with fl(a/w) <= L
__device__ float exact_hi(float w, float L)
{
    float a = L * w;
    while (a / w > L)            a = next_dn(a);
    while (next_up(a) / w <= L)  a = next_up(a);
    return a;
}

// record layout (floats unless noted):
//  0-2  t      3-6  q(normalized)    7-9  invw=fl(1/w)
// 10-12 (S-1)f 13-15 A (exact lo)   16-18 B (exact hi)
// 19 (int) m*sdf_stride  20-22 (int) SX,SY,SZ  23 pad
// 24-26 world AABB lo    27-29 world AABB hi   30-31 pad
__global__ void prep_v4(const int* __restrict__ shapes,
                        const int* __restrict__ indices,
                        const float* __restrict__ poses,
                        const float* __restrict__ widths,
                        float* __restrict__ rec,
                        int BN, int sdf_stride)
{
    int bn = blockIdx.x * blockDim.x + threadIdx.x;
    if (bn >= BN) return;
    int m = indices[bn];
    const float* pp = poses + (size_t)bn * 7;
    float tx = pp[0], ty = pp[1], tz = pp[2];
    float qx = pp[3], qy = pp[4], qz = pp[5], qw = pp[6];
    // identical op order to validated rounds -> bit-identical q
    float nrm = sqrtf(qx * qx + qy * qy + qz * qz + qw * qw);
    qx = qx / nrm; qy = qy / nrm; qz = qz / nrm; qw = qw / nrm;

    float wx = widths[bn * 3 + 0], wy = widths[bn * 3 + 1], wz = widths[bn * 3 + 2];
    int SX = shapes[m * 3 + 0], SY = shapes[m * 3 + 1], SZ = shapes[m * 3 + 2];
    float mx = (float)(SX - 1), my = (float)(SY - 1), mz = (float)(SZ - 1);

    // inside_x <=> fl(rx/w) in [0.5, mx+0.5] <=> rx in [A,B] (division monotone,
    // u-0.5 Sterbenz-exact on the decision range) — validated rounds 2-4
    float Ax = exact_lo(wx, 0.5f), Ay = exact_lo(wy, 0.5f), Az = exact_lo(wz, 0.5f);
    float Bx = exact_hi(wx, mx + 0.5f), By = exact_hi(wy, my + 0.5f), Bz = exact_hi(wz, mz + 0.5f);

    // rotation matrix (local->world) from q, for conservative world AABB
    float xx = qx * qx, yy = qy * qy, zz = qz * qz;
    float xy = qx * qy, xz = qx * qz, yz = qy * qz;
    float wqx = qw * qx, wqy = qw * qy, wqz = qw * qz;
    float R00 = 1.0f - 2.0f * (yy + zz), R01 = 2.0f * (xy - wqz), R02 = 2.0f * (xz + wqy);
    float R10 = 2.0f * (xy + wqz), R11 = 1.0f - 2.0f * (xx + zz), R12 = 2.0f * (yz - wqx);
    float R20 = 2.0f * (xz - wqy), R21 = 2.0f * (yz + wqx), R22 = 1.0f - 2.0f * (xx + yy);

    float cx = 0.5f * (Ax + Bx), cy = 0.5f * (Ay + By), cz = 0.5f * (Az + Bz);
    float hx = 0.5f * (Bx - Ax), hy = 0.5f * (By - Ay), hz = 0.5f * (Bz - Az);
    const float MARG = 2e-3f;  // >> rotation/rounding error (~1e-6)

    float wcx = tx + R00 * cx + R01 * cy + R02 * cz;
    float wcy = ty + R10 * cx + R11 * cy + R12 * cz;
    float wcz = tz + R20 * cx + R21 * cy + R22 * cz;
    float ex = fabsf(R00) * hx + fabsf(R01) * hy + fabsf(R02) * hz + MARG;
    float ey = fabsf(R10) * hx + fabsf(R11) * hy + fabsf(R12) * hz + MARG;
    float ez = fabsf(R20) * hx + fabsf(R21) * hy + fabsf(R22) * hz + MARG;

    float* r = rec + (size_t)bn * RECSZ;
    r[0] = tx;  r[1] = ty;  r[2] = tz;
    r[3] = qx;  r[4] = qy;  r[5] = qz;  r[6] = qw;
    r[7] = 1.0f / wx; r[8] = 1.0f / wy; r[9] = 1.0f / wz;
    r[10] = mx; r[11] = my; r[12] = mz;
    r[13] = Ax; r[14] = Ay; r[15] = Az;
    r[16] = Bx; r[17] = By; r[18] = Bz;
    int* ri = (int*)r;
    ri[19] = m * sdf_stride;
    ri[20] = SX; ri[21] = SY; ri[22] = SZ;
    r[23] = 0.0f;
    r[24] = wcx - ex; r[25] = wcy - ey; r[26] = wcz - ez;
    r[27] = wcx + ex; r[28] = wcy + ey; r[29] = wcz + ez;
    r[30] = 0.0f; r[31] = 0.0f;
}

// per-(batch, 256-thread block) conservative SDF overlap mask (bit n set = may touch)
__global__ void prep_mask(const float* __restrict__ rec,
                          unsigned int* __restrict__ mask,
                          int N, int totalBlocks)
{
    int gid = blockIdx.x * blockDim.x + threadIdx.x;
    if (gid >= totalBlocks) return;
    int b  = gid / BLOCKS_PER_B;
    int bx = gid % BLOCKS_PER_B;

    int pid0 = bx * 256;               // block spans pids [pid0, pid0+255]
    int col0 = pid0 / GZD;
    int col2 = (pid0 + 255) / GZD;
    int x  = col0 / GYD;               // single x-slab (9216 pts = 36 blocks)
    int y0 = col0 % GYD;
    int y2 = col2 % GYD;               // y2 >= y0, no wrap within slab

    float px  = GLOWER + ((float)x + 0.5f) * GSTEP;
    float pyl = GLOWER + ((float)y0 + 0.5f) * GSTEP;
    float pyh = GLOWER + ((float)y2 + 0.5f) * GSTEP;
    float pzl = GLOWER + 0.5f * GSTEP;
    float pzh = GLOWER + ((float)(GZD - 1) + 0.5f) * GSTEP;

    unsigned int msk = 0u;
    for (int n = 0; n < N; ++n) {
        const float* r = rec + (size_t)(b * N + n) * RECSZ;
        bool ok = (px  >= r[24]) & (px  <= r[27]) &
                  (pyh >= r[25]) & (pyl <= r[28]) &
                  (pzh >= r[26]) & (pzl <= r[29]);
        msk |= (ok ? 1u : 0u) << n;
    }
    mask[gid] = msk;
}

__device__ __forceinline__ float trilerp(const float* __restrict__ sd,
                                         float rx, float ry, float rz,
                                         float invwx, float invwy, float invwz,
                                         float mx, float my, float mz,
                                         int SX, int SY, int SZ)
{
    // reciprocal-mul g: affects interpolated VALUE only at ~ulp level;
    // the inside/outside decision was already made exactly via [A,B].
    float gx = rx * invwx - 0.5f;
    float gy = ry * invwy - 0.5f;
    float gz = rz * invwz - 0.5f;
    float fx = fminf(fmaxf(gx, 0.0f), mx);
    float fy = fminf(fmaxf(gy, 0.0f), my);
    float fz = fminf(fmaxf(gz, 0.0f), mz);
    int i0x = (int)fx, i0y = (int)fy, i0z = (int)fz;  // f>=0 -> trunc==floor
    float frx = fx - (float)i0x;
    float fry = fy - (float)i0y;
    float frz = fz - (float)i0z;
    int i1x = min(i0x + 1, SX - 1);
    int i1y = min(i0y + 1, SY - 1);
    int i1z = min(i0z + 1, SZ - 1);
    int b00 = (i0x * SY + i0y) * SZ;
    int b01 = (i0x * SY + i1y) * SZ;
    int b10 = (i1x * SY + i0y) * SZ;
    int b11 = (i1x * SY + i1y) * SZ;
    float v000 = sd[b00 + i0z], v001 = sd[b00 + i1z];
    float v010 = sd[b01 + i0z], v011 = sd[b01 + i1z];
    float v100 = sd[b10 + i0z], v101 = sd[b10 + i1z];
    float v110 = sd[b11 + i0z], v111 = sd[b11 + i1z];
    float c00 = v000 + frz * (v001 - v000);
    float c01 = v010 + frz * (v011 - v010);
    float c10 = v100 + frz * (v101 - v100);
    float c11 = v110 + frz * (v111 - v110);
    float c0 = c00 + fry * (c01 - c00);
    float c1 = c10 + fry * (c11 - c10);
    return c0 + frx * (c1 - c0);
}

__global__ __launch_bounds__(256) void sdf_grid_v4(
    const float* __restrict__ sdfs,
    const float* __restrict__ rec,
    const unsigned int* __restrict__ mask,
    float* __restrict__ out,
    int N)
{
    int pid = blockIdx.x * blockDim.x + threadIdx.x;  // z innermost
    int b = blockIdx.y;

    int z = pid % GZD;
    int y = (pid / GZD) % GYD;
    int x = pid / (GZD * GYD);

    float px = GLOWER + ((float)x + 0.5f) * GSTEP;
    float py = GLOWER + ((float)y + 0.5f) * GSTEP;
    float pz = GLOWER + ((float)z + 0.5f) * GSTEP;

    unsigned int msk = mask[b * BLOCKS_PER_B + blockIdx.x];  // uniform -> s_load

    float best = BIGF;

    for (int n = 0; n < N; ++n) {
        if (!((msk >> n) & 1u)) continue;  // whole block certainly outside SDF n

        const float* r = rec + (size_t)(b * N + n) * RECSZ;  // wave-uniform -> s_load
        float dx = px - r[0], dy = py - r[1], dz = pz - r[2];
        float rx, ry, rz;
        rot_inv(r[3], r[4], r[5], r[6], dx, dy, dz, rx, ry, rz);

        // single exact inside test, no divisions (validated rounds 2-4)
        bool inside = (rx >= r[13]) & (rx <= r[16]) &
                      (ry >= r[14]) & (ry <= r[17]) &
                      (rz >= r[15]) & (rz <= r[18]);
        if (inside) {
            const int* ri = (const int*)r;
            float v = trilerp(sdfs + ri[19], rx, ry, rz,
                              r[7], r[8], r[9], r[10], r[11], r[12],
                              ri[20], ri[21], ri[22]);
            best = fminf(best, v);
        }
    }

    out[(size_t)b * PTS_PER_B + pid] = best;
}

// ---------------- fallback: round-0 validated monolithic kernel ----------------
__global__ __launch_bounds__(256) void sdf_grid_kernel(
    const float* __restrict__ sdfs,
    const int*   __restrict__ sdf_shapes,
    const int*   __restrict__ indices,
    const float* __restrict__ poses,
    const float* __restrict__ widths,
    float*       __restrict__ out,
    int total, int N, int sdf_stride)
{
    int idx = blockIdx.x * blockDim.x + threadIdx.x;
    if (idx >= total) return;
    int z = idx % GZD;
    int y = (idx / GZD) % GYD;
    int x = (idx / (GZD * GYD)) % GXD;
    int b = idx / (GZD * GYD * GXD);
    float px = GLOWER + ((float)x + 0.5f) * GSTEP;
    float py = GLOWER + ((float)y + 0.5f) * GSTEP;
    float pz = GLOWER + ((float)z + 0.5f) * GSTEP;
    float best = BIGF;
    for (int n = 0; n < N; ++n) {
        int bn = b * N + n;
        int m  = indices[bn];
        const float* pp = poses + (size_t)bn * 7;
        float tx = pp[0], ty = pp[1], tz = pp[2];
        float qx = pp[3], qy = pp[4], qz = pp[5], qw = pp[6];
        float nrm = sqrtf(qx * qx + qy * qy + qz * qz + qw * qw);
        qx = qx / nrm; qy = qy / nrm; qz = qz / nrm; qw = qw / nrm;
        float dx = px - tx, dy = py - ty, dz = pz - tz;
        float rx, ry, rz;
        rot_inv(qx, qy, qz, qw, dx, dy, dz, rx, ry, rz);
        const float* ww = widths + (size_t)bn * 3;
        float gx = rx / ww[0] - 0.5f;
        float gy = ry / ww[1] - 0.5f;
        float gz = rz / ww[2] - 0.5f;
        int SX = sdf_shapes[m * 3 + 0];
        int SY = sdf_shapes[m * 3 + 1];
        int SZ = sdf_shapes[m * 3 + 2];
        float mx = (float)(SX - 1), my = (float)(SY - 1), mz = (float)(SZ - 1);
        bool inside = (gx >= 0.0f) && (gx <= mx) &&
                      (gy >= 0.0f) && (gy <= my) &&
                      (gz >= 0.0f) && (gz <= mz);
        float fx = fminf(fmaxf(gx, 0.0f), mx);
        float fy = fminf(fmaxf(gy, 0.0f), my);
        float fz = fminf(fmaxf(gz, 0.0f), mz);
        int i0x = (int)floorf(fx), i0y = (int)floorf(fy), i0z = (int)floorf(fz);
        float frx = fx - (float)i0x, fry = fy - (float)i0y, frz = fz - (float)i0z;
        int i1x = min(i0x + 1, SX - 1);
        int i1y = min(i0y + 1, SY - 1);
        int i1z = min(i0z + 1, SZ - 1);
        const float* sd = sdfs + (size_t)m * sdf_stride;
        int b00 = (i0x * SY + i0y) * SZ;
        int b01 = (i0x * SY + i1y) * SZ;
        int b10 = (i1x * SY + i0y) * SZ;
        int b11 = (i1x * SY + i1y) * SZ;
        float v000 = sd[b00 + i0z], v001 = sd[b00 + i1z];
        float v010 = sd[b01 + i0z], v011 = sd[b01 + i1z];
        float v100 = sd[b10 + i0z], v101 = sd[b10 + i1z];
        float v110 = sd[b11 + i0z], v111 = sd[b11 + i1z];
        float wx0 = 1.0f - frx, wx1 = frx;
        float wy0 = 1.0f - fry, wy1 = fry;
        float wz0 = 1.0f - frz, wz1 = frz;
        float acc = wx0 * wy0 * wz0 * v000 + wx0 * wy0 * wz1 * v001
                  + wx0 * wy1 * wz0 * v010 + wx0 * wy1 * wz1 * v011
                  + wx1 * wy0 * wz0 * v100 + wx1 * wy0 * wz1 * v101
                  + wx1 * wy1 * wz0 * v110 + wx1 * wy1 * wz1 * v111;
        float val = inside ? acc : BIGF;
        best = fminf(best, val);
    }
    out[idx] = best;
}

extern "C" void kernel_launch(void* const* d_in, const int* in_sizes, int n_in,
                              void* d_out, int out_size, void* d_ws, size_t ws_size,
                              hipStream_t stream) {
    const float* sdfs    = (const float*)d_in[0];
    const int*   shapes  = (const int*)d_in[1];
    const int*   indices = (const int*)d_in[2];
    const float* poses   = (const float*)d_in[3];
    const float* widths  = (const float*)d_in[4];
    float*       out     = (float*)d_out;

    int M = in_sizes[1] / 3;           // sdf_shapes is (M,3)
    int sdf_stride = in_sizes[0] / M;  // elements per SDF volume
    int B = out_size / PTS_PER_B;
    int N = in_sizes[2] / B;           // indices is (B,N)
    int BN = B * N;
    int totalBlocks = B * BLOCKS_PER_B;

    size_t rec_bytes  = (size_t)BN * RECSZ * sizeof(float);
    size_t rec_pad    = (rec_bytes + 255) & ~(size_t)255;
    size_t mask_bytes = (size_t)totalBlocks * sizeof(unsigned int);
    size_t ws_needed  = rec_pad + mask_bytes;

    if (ws_size >= ws_needed && N <= 32 && (PTS_PER_B % 256) == 0) {
        float* rec = (float*)d_ws;
        unsigned int* mask = (unsigned int*)((char*)d_ws + rec_pad);

        prep_v4<<<(BN + 63) / 64, 64, 0, stream>>>(
            shapes, indices, poses, widths, rec, BN, sdf_stride);
        prep_mask<<<(totalBlocks + 255) / 256, 256, 0, stream>>>(
            rec, mask, N, totalBlocks);
        dim3 grid(BLOCKS_PER_B, B);
        sdf_grid_v4<<<grid, 256, 0, stream>>>(sdfs, rec, mask, out, N);
    } else {
        int total = out_size;
        int blocks = (total + 255) / 256;
        sdf_grid_kernel<<<blocks, 256, 0, stream>>>(
            sdfs, shapes, indices, poses, widths, out, total, N, sdf_stride);
    }
}